// Round 2
// baseline (96.118 us; speedup 1.0000x reference)
//
#include <hip/hip_runtime.h>

// Router: out[t] = x[t] @ W[split[t]] + b[split[t]]
// N=262144 tokens, D=128, E=8 experts. fp32 in/out, bf16 MFMA compute.

typedef __bf16 bf16x8 __attribute__((ext_vector_type(8)));
typedef unsigned short u16x8 __attribute__((ext_vector_type(8)));
typedef float f32x4 __attribute__((ext_vector_type(4)));

__device__ __forceinline__ unsigned short f2bf(float f) {
    unsigned u = __builtin_bit_cast(unsigned, f);
    u += 0x7FFFu + ((u >> 16) & 1u);   // round-to-nearest-even
    return (unsigned short)(u >> 16);
}

// meta layout (ints): [0..7]=counts, [8..15]=cursors
__global__ void k_init(int* meta) {
    if (threadIdx.x < 16) meta[threadIdx.x] = 0;
}

// Transpose + convert W[e][f][g] (f32) -> Wt[e][g][f] (bf16).
// 64 blocks: (expert e = bid>>3, g-chunk of 16 = bid&7)
__global__ void k_wt(const float* __restrict__ W, unsigned short* __restrict__ Wt) {
    __shared__ float T[16][132];
    int e = blockIdx.x >> 3;
    int g0 = (blockIdx.x & 7) << 4;
    const float* We = W + e * 128 * 128;
    #pragma unroll
    for (int i = 0; i < 2; ++i) {
        int idx = i * 256 + threadIdx.x;   // 0..511 float4 loads
        int f = idx >> 2, q = idx & 3;
        float4 v = *(const float4*)(We + f * 128 + g0 + q * 4);
        T[q * 4 + 0][f] = v.x; T[q * 4 + 1][f] = v.y;
        T[q * 4 + 2][f] = v.z; T[q * 4 + 3][f] = v.w;
    }
    __syncthreads();
    int g = threadIdx.x >> 4, fc = threadIdx.x & 15;
    u16x8 o;
    #pragma unroll
    for (int j = 0; j < 8; ++j) o[j] = f2bf(T[g][fc * 8 + j]);
    *(u16x8*)(Wt + ((e * 128 + g0 + g) * 128 + fc * 8)) = o;
}

__global__ void k_hist(const int* __restrict__ split, int* __restrict__ meta) {
    __shared__ int h[8];
    if (threadIdx.x < 8) h[threadIdx.x] = 0;
    __syncthreads();
    int t = blockIdx.x * 256 + threadIdx.x;
    atomicAdd(&h[split[t]], 1);
    __syncthreads();
    if (threadIdx.x < 8) atomicAdd(&meta[threadIdx.x], h[threadIdx.x]);
}

// Scatter token ids into per-expert contiguous segments of perm.
__global__ void k_scatter(const int* __restrict__ split, int* __restrict__ meta,
                          int* __restrict__ perm) {
    __shared__ int h[8], base[8];
    if (threadIdx.x < 8) h[threadIdx.x] = 0;
    __syncthreads();
    int t = blockIdx.x * 256 + threadIdx.x;
    int e = split[t];
    int r = atomicAdd(&h[e], 1);
    __syncthreads();
    if (threadIdx.x < 8)
        base[threadIdx.x] = atomicAdd(&meta[8 + threadIdx.x], h[threadIdx.x]);
    __syncthreads();
    // exclusive prefix of counts = segment offset for expert e
    int off = 0;
    #pragma unroll
    for (int ee = 0; ee < 8; ++ee) off += (ee < e) ? meta[ee] : 0;
    perm[off + base[e] + r] = t;
}

// One 256-token x 128-col tile per block. 8 waves; wave w owns rows [w*32, w*32+32).
__global__ __launch_bounds__(512) void k_gemm(
    const float* __restrict__ x, const float* __restrict__ bias,
    const int* __restrict__ meta, const int* __restrict__ perm,
    const unsigned short* __restrict__ Wt, float* __restrict__ out) {

    // map block -> (expert, tile)
    int bid = blockIdx.x;
    int e = -1, tile = 0, cnt_e = 0, off_e = 0;
    int acc_t = 0, off = 0;
    #pragma unroll
    for (int ee = 0; ee < 8; ++ee) {
        int c = meta[ee];
        int t = (c + 255) >> 8;
        if (e < 0 && bid < acc_t + t) { e = ee; tile = bid - acc_t; cnt_e = c; off_e = off; }
        acc_t += t;
        off += c;
    }
    if (e < 0) return;

    __shared__ unsigned short Wl[16384];   // 32 KB, [g][f] bf16 in swizzled 16B chunks

    int tid = threadIdx.x;
    int lane = tid & 63;
    int w = tid >> 6;
    int l15 = lane & 15, lq = lane >> 4;

    // stage Wt[e] -> LDS; slot(g,fc) = g*16 + (fc ^ (g&7)) breaks the 16-way
    // bank conflict on stride-256B B-fragment reads.
    const unsigned short* We = Wt + e * 16384;
    #pragma unroll
    for (int i = 0; i < 4; ++i) {
        int c = i * 512 + tid;             // chunk 0..2047
        int g = c >> 4, fc = c & 15;
        int slot = (g << 4) | (fc ^ (g & 7));
        *(u16x8*)(Wl + slot * 8) = *(const u16x8*)(We + c * 8);
    }

    // A fragments direct from global x (no LDS round-trip), f32 -> bf16 RNE.
    // A layout: row = lane&15, k = (lane>>4)*8 + j
    bf16x8 afrag[2][4];
    #pragma unroll
    for (int i = 0; i < 2; ++i) {
        int p = tile * 256 + w * 32 + i * 16 + l15;
        int pp = p < cnt_e ? p : cnt_e - 1;
        int tok = perm[off_e + pp];
        const float* xr = x + (long)tok * 128 + lq * 8;
        #pragma unroll
        for (int kk = 0; kk < 4; ++kk) {
            float4 lo = *(const float4*)(xr + kk * 32);
            float4 hi = *(const float4*)(xr + kk * 32 + 4);
            u16x8 u;
            u[0] = f2bf(lo.x); u[1] = f2bf(lo.y); u[2] = f2bf(lo.z); u[3] = f2bf(lo.w);
            u[4] = f2bf(hi.x); u[5] = f2bf(hi.y); u[6] = f2bf(hi.z); u[7] = f2bf(hi.w);
            afrag[i][kk] = __builtin_bit_cast(bf16x8, u);
        }
    }

    __syncthreads();

    f32x4 acc[2][8];
    #pragma unroll
    for (int i = 0; i < 2; ++i)
        #pragma unroll
        for (int j = 0; j < 8; ++j) acc[i][j] = (f32x4){0.f, 0.f, 0.f, 0.f};

    // B layout: col = lane&15, k = (lane>>4)*8 + j
    #pragma unroll
    for (int kk = 0; kk < 4; ++kk) {
        #pragma unroll
        for (int j = 0; j < 8; ++j) {
            int g = j * 16 + l15;
            int fc = kk * 4 + lq;
            int slot = (g << 4) | (fc ^ (g & 7));
            bf16x8 b = *(const bf16x8*)(Wl + slot * 8);
            acc[0][j] = __builtin_amdgcn_mfma_f32_16x16x32_bf16(afrag[0][kk], b, acc[0][j], 0, 0, 0);
            acc[1][j] = __builtin_amdgcn_mfma_f32_16x16x32_bf16(afrag[1][kk], b, acc[1][j], 0, 0, 0);
        }
    }

    // bias per output column
    float bv[8];
    #pragma unroll
    for (int j = 0; j < 8; ++j) bv[j] = bias[e * 128 + j * 16 + l15];

    // C/D layout: col = lane&15, row = (lane>>4)*4 + reg
    #pragma unroll
    for (int i = 0; i < 2; ++i) {
        #pragma unroll
        for (int r = 0; r < 4; ++r) {
            int p = tile * 256 + w * 32 + i * 16 + lq * 4 + r;
            if (p < cnt_e) {
                int tok = perm[off_e + p];
                float* o = out + (long)tok * 128 + l15;
                #pragma unroll
                for (int j = 0; j < 8; ++j) o[j * 16] = acc[i][j][r] + bv[j];
            }
        }
    }
}

extern "C" void kernel_launch(void* const* d_in, const int* in_sizes, int n_in,
                              void* d_out, int out_size, void* d_ws, size_t ws_size,
                              hipStream_t stream) {
    const float* x     = (const float*)d_in[0];
    const int*   split = (const int*)d_in[1];
    const float* W     = (const float*)d_in[2];
    const float* bias  = (const float*)d_in[3];
    float* out = (float*)d_out;

    int n = in_sizes[1];                  // 262144 tokens
    char* ws = (char*)d_ws;
    int* meta = (int*)ws;                                   // counts[8], cursors[8]
    int* perm = (int*)(ws + 4096);                          // n ints
    unsigned short* Wt = (unsigned short*)(ws + 4096 + (size_t)n * 4); // 8*128*128 bf16

    k_init<<<1, 64, 0, stream>>>(meta);
    k_wt<<<64, 256, 0, stream>>>(W, Wt);
    k_hist<<<n / 256, 256, 0, stream>>>(split, meta);
    k_scatter<<<n / 256, 256, 0, stream>>>(split, meta, perm);
    k_gemm<<<n / 256 + 8, 512, 0, stream>>>(x, bias, meta, perm, Wt, out);
}

// Round 3
// 83.017 us; speedup vs baseline: 1.1578x; 1.1578x over previous
//
#include <hip/hip_runtime.h>

// Router: out[t] = x[t] @ W[split[t]] + b[split[t]]
// N=262144, D=128, E=8. fp32 in/out, bf16 MFMA.
// R3: natural-order fused kernel — streaming x reads, in-block bucketing via
// LDS, per-wave 16-col slices with W fragments from L2. No global perm/gather.

typedef __bf16 bf16x8 __attribute__((ext_vector_type(8)));
typedef unsigned short u16x8 __attribute__((ext_vector_type(8)));
typedef float f32x4 __attribute__((ext_vector_type(4)));

__device__ __forceinline__ unsigned short f2bf(float f) {
    unsigned u = __builtin_bit_cast(unsigned, f);
    u += 0x7FFFu + ((u >> 16) & 1u);   // RNE
    return (unsigned short)(u >> 16);
}
__device__ __forceinline__ unsigned pack2(float a, float b) {
    return (unsigned)f2bf(a) | ((unsigned)f2bf(b) << 16);
}

// Transpose + convert W[e][f][g] (f32) -> Wt[e][g][f] (bf16).
__global__ void k_wt(const float* __restrict__ W, unsigned short* __restrict__ Wt) {
    __shared__ float T[16][132];
    int e = blockIdx.x >> 3;
    int g0 = (blockIdx.x & 7) << 4;
    const float* We = W + e * 128 * 128;
    #pragma unroll
    for (int i = 0; i < 2; ++i) {
        int idx = i * 256 + threadIdx.x;
        int f = idx >> 2, q = idx & 3;
        float4 v = *(const float4*)(We + f * 128 + g0 + q * 4);
        T[q * 4 + 0][f] = v.x; T[q * 4 + 1][f] = v.y;
        T[q * 4 + 2][f] = v.z; T[q * 4 + 3][f] = v.w;
    }
    __syncthreads();
    int g = threadIdx.x >> 4, fc = threadIdx.x & 15;
    u16x8 o;
    #pragma unroll
    for (int j = 0; j < 8; ++j) o[j] = f2bf(T[g][fc * 8 + j]);
    *(u16x8*)(Wt + ((e * 128 + g0 + g) * 128 + fc * 8)) = o;
}

#define NT 256     // tokens per block

__global__ __launch_bounds__(512) void k_fused(
    const float* __restrict__ x, const int* __restrict__ split,
    const float* __restrict__ bias, const unsigned short* __restrict__ Wt,
    float* __restrict__ out) {

    // A-tile: NT rows x 128 bf16, 16B chunks swizzled: chunk fc of row s at
    // elem offset ((fc ^ (s&7))*8) — kills the stride-256B bank conflict.
    __shared__ unsigned short A[NT * 128];            // 64 KB
    __shared__ int hcnt[8], startE[8];
    __shared__ int dest[NT], trow[NT];
    __shared__ int exT[24], rbT[24], limT[24];
    __shared__ int Tn;

    const int tid = threadIdx.x;
    const long t0 = (long)blockIdx.x * NT;

    if (tid < 8) hcnt[tid] = 0;
    __syncthreads();

    // phase A: issue streaming x loads (block reads its 128KB contiguously;
    // chunk c = rr*512+tid of 16B -> row c>>5, k-offset (c&31)*4 floats)
    float4 xv[16];
    const float* xb = x + t0 * 128;
    #pragma unroll
    for (int rr = 0; rr < 16; ++rr)
        xv[rr] = *(const float4*)(xb + (rr * 512 + tid) * 4);

    int e = 0, rank = 0;
    if (tid < NT) {
        e = split[t0 + tid];
        rank = atomicAdd(&hcnt[e], 1);
    }
    __syncthreads();

    if (tid == 0) {
        int acc = 0, T = 0;
        for (int ee = 0; ee < 8; ++ee) {
            int c = hcnt[ee];
            startE[ee] = acc;
            for (int k = 0; k < c; k += 16) {
                exT[T] = ee; rbT[T] = acc + k;
                limT[T] = (c - k < 16) ? (c - k) : 16; T++;
            }
            acc += c;
        }
        Tn = T;
    }
    __syncthreads();

    if (tid < NT) {
        int s = startE[e] + rank;   // bucketed slot, bijective over [0,NT)
        dest[tid] = s;
        trow[s] = tid;
    }
    __syncthreads();

    // phase B: cvt f32->bf16 and scatter rows into bucketed LDS order
    #pragma unroll
    for (int rr = 0; rr < 16; ++rr) {
        int c = rr * 512 + tid;
        int row = c >> 5;
        int s = dest[row];
        int fc = (c & 31) >> 1;
        int half = c & 1;
        unsigned d0 = pack2(xv[rr].x, xv[rr].y);
        unsigned d1 = pack2(xv[rr].z, xv[rr].w);
        unsigned short* p = A + s * 128 + ((fc ^ (s & 7)) << 3) + half * 4;
        *(uint2*)p = make_uint2(d0, d1);
    }
    __syncthreads();

    // phase C: per-wave 16-col slice; iterate expert-group tiles
    const int lane = tid & 63, w = tid >> 6;
    const int l15 = lane & 15, lq = lane >> 4;
    const int T = Tn;

    bf16x8 bfrag[4];
    float bv = 0.f;
    int preve = -1;

    for (int tau = 0; tau < T; ++tau) {
        int ee = exT[tau], rb = rbT[tau], lim = limT[tau];
        if (ee != preve) {
            preve = ee;
            const unsigned short* Wb = Wt + ee * 16384 + (w * 16 + l15) * 128;
            #pragma unroll
            for (int kk = 0; kk < 4; ++kk)
                bfrag[kk] = *(const bf16x8*)(Wb + (kk * 4 + lq) * 8);
            bv = bias[ee * 128 + w * 16 + l15];
        }
        int srow = rb + l15;
        srow = srow < NT - 1 ? srow : NT - 1;   // clamp LDS addr; garbage rows unused
        f32x4 acc = {0.f, 0.f, 0.f, 0.f};
        #pragma unroll
        for (int kk = 0; kk < 4; ++kk) {
            int fc = kk * 4 + lq;
            bf16x8 a = *(const bf16x8*)(A + srow * 128 + ((fc ^ (srow & 7)) << 3));
            acc = __builtin_amdgcn_mfma_f32_16x16x32_bf16(a, bfrag[kk], acc, 0, 0, 0);
        }
        // D layout: col = l15 (-> out col w*16+l15), row = lq*4+r
        #pragma unroll
        for (int r = 0; r < 4; ++r) {
            int ri = lq * 4 + r;
            if (ri < lim) {
                int tokl = trow[rb + ri];
                out[(t0 + tokl) * 128 + w * 16 + l15] = acc[r] + bv;
            }
        }
    }
}

extern "C" void kernel_launch(void* const* d_in, const int* in_sizes, int n_in,
                              void* d_out, int out_size, void* d_ws, size_t ws_size,
                              hipStream_t stream) {
    const float* x     = (const float*)d_in[0];
    const int*   split = (const int*)d_in[1];
    const float* W     = (const float*)d_in[2];
    const float* bias  = (const float*)d_in[3];
    float* out = (float*)d_out;

    int n = in_sizes[1];                      // 262144
    unsigned short* Wt = (unsigned short*)d_ws;   // 8*128*128 bf16 = 256 KB

    k_wt<<<64, 256, 0, stream>>>(W, Wt);
    k_fused<<<n / NT, 512, 0, stream>>>(x, split, bias, Wt, out);
}